// Round 4
// baseline (630.963 us; speedup 1.0000x reference)
//
#include <hip/hip_runtime.h>
#include <hip/hip_bf16.h>

#define NN 50000
#define EE 800000
#define FIN 500
#define H1D 300
#define H2D 100
#define CC 16

// ---------- dtype-flexible load helpers ----------
__device__ __forceinline__ float ldf(const void* p, size_t i, int isbf16) {
    return isbf16 ? __bfloat162float(((const __hip_bfloat16*)p)[i])
                  : ((const float*)p)[i];
}
__device__ __forceinline__ int ld_src(const int* ei, int e, int is64) {
    return is64 ? ei[2 * (size_t)e] : ei[e];
}
__device__ __forceinline__ int ld_dst(const int* ei, int e, int is64) {
    return is64 ? ei[2 * ((size_t)EE + e)] : ei[(size_t)EE + e];
}

// split fp32 -> hi/lo bf16 bit patterns (hi+lo captures ~17 mantissa bits)
__device__ __forceinline__ void split2(float f, unsigned short& h, unsigned short& l) {
    __bf16 hb = (__bf16)f;
    float fh = (float)hb;
    __bf16 lb = (__bf16)(f - fh);
    h = __builtin_bit_cast(unsigned short, hb);
    l = __builtin_bit_cast(unsigned short, lb);
}

// unpack 2 packed bf16 (low = even feature, high = odd feature) to float2
__device__ __forceinline__ float2 bf2f2(unsigned int v) {
    float lo = __builtin_bit_cast(float, v << 16);
    float hi = __builtin_bit_cast(float, v & 0xffff0000u);
    return make_float2(lo, hi);
}

// ---------- dtype sniffing ----------
// flags[0]=1 if floats are stored as bf16, 0 if fp32.
// flags[1]=1 if edge_index is int64, 0 if int32.
__global__ void k_sniff(const unsigned short* __restrict__ xw,
                        const unsigned int* __restrict__ ew,
                        int* __restrict__ flags) {
    __shared__ int c_sane, c_zero;
    if (threadIdx.x == 0) { c_sane = 0; c_zero = 0; }
    __syncthreads();
    int t = threadIdx.x;  // 256 threads, 4 samples each
    int sane = 0, zer = 0;
    for (int j = 0; j < 4; j++) {
        unsigned short w = xw[t * 4 + j];
        int ex = (w >> 7) & 0xFF;
        if (w == 0 || (ex >= 100 && ex <= 150)) sane++;     // plausible bf16 of N(0,1)
        if (ew[2 * (t * 4 + j) + 1] == 0u) zer++;           // int64 high words
    }
    atomicAdd(&c_sane, sane);
    atomicAdd(&c_zero, zer);
    __syncthreads();
    if (threadIdx.x == 0) {
        flags[0] = (c_sane > 820) ? 1 : 0;  // >80% of 1024
        flags[1] = (c_zero > 512) ? 1 : 0;  // >50% of 1024
    }
}

// ---------- degree / CSR build ----------
__global__ void k_zero_cnt(int* __restrict__ cnt) {
    int i = blockIdx.x * blockDim.x + threadIdx.x;
    if (i < NN) cnt[i] = 0;
}

__global__ void k_hist(const int* __restrict__ ei, int* __restrict__ cnt,
                       const int* __restrict__ flags) {
    int e = blockIdx.x * blockDim.x + threadIdx.x;
    int is64 = flags[1];
    if (e < EE) {
        int d = ld_dst(ei, e, is64);
        if ((unsigned)d < NN) atomicAdd(&cnt[d], 1);
    }
}

__global__ void k_dinv(const int* __restrict__ cnt, float* __restrict__ dinv) {
    int i = blockIdx.x * blockDim.x + threadIdx.x;
    if (i < NN) dinv[i] = rsqrtf((float)cnt[i] + 1.0f);  // +1 self loop, deg>=1
}

__global__ __launch_bounds__(1024) void k_scan(int* __restrict__ cnt, int* __restrict__ row_ptr) {
    const int T = 1024;
    const int chunk = (NN + T - 1) / T;  // 49
    int t = threadIdx.x;
    int lo = t * chunk;
    int hi = lo + chunk; if (hi > NN) hi = NN; if (lo > NN) lo = NN;
    int s = 0;
    for (int i = lo; i < hi; i++) s += cnt[i];
    __shared__ int sums[T];
    sums[t] = s;
    __syncthreads();
    for (int off = 1; off < T; off <<= 1) {
        int v = (t >= off) ? sums[t - off] : 0;
        __syncthreads();
        sums[t] += v;
        __syncthreads();
    }
    int run = sums[t] - s;  // exclusive prefix
    for (int i = lo; i < hi; i++) {
        int c = cnt[i];
        row_ptr[i] = run;
        run += c;
        cnt[i] = 0;  // reuse cnt as fill counter for scatter
    }
    if (t == T - 1) row_ptr[NN] = run;
}

__global__ void k_scatter(const int* __restrict__ ei, const int* __restrict__ row_ptr,
                          int* __restrict__ fill, int* __restrict__ csr_src,
                          const int* __restrict__ flags) {
    int e = blockIdx.x * blockDim.x + threadIdx.x;
    int is64 = flags[1];
    if (e < EE) {
        int s = ld_src(ei, e, is64);
        int d = ld_dst(ei, e, is64);
        if ((unsigned)d < NN) {
            int pos = row_ptr[d] + atomicAdd(&fill[d], 1);
            csr_src[pos] = s;
        }
    }
}

// ---------- bf16-input fallback tiled GEMM (runs only when flags[0]==1) ----------
template <bool A_DYN, bool RELU, bool SCALE, bool OUTBF>
__global__ __launch_bounds__(256) void k_gemm(const void* __restrict__ A,
                                              const void* __restrict__ B,
                                              const void* __restrict__ bias,
                                              const float* __restrict__ dinv,
                                              void* __restrict__ C,
                                              int M, int K, int Nn,
                                              const int* __restrict__ flags) {
    if (!flags[0]) return;  // fp32 mode handled by split-MFMA kernel
    __shared__ float As[16][68];  // [k][m], padded
    __shared__ float Bs[16][68];  // [k][n]
    const int bf = flags[0];
    const int tid = threadIdx.x;
    const int m0 = blockIdx.x * 64, n0 = blockIdx.y * 64;
    const int tx = tid & 15;   // n group (4 cols)
    const int ty = tid >> 4;   // m group (4 rows)
    float acc[4][4] = {};

    for (int kc = 0; kc < K; kc += 16) {
#pragma unroll
        for (int j = 0; j < 4; j++) {
            int idx = tid + j * 256;
            int kk = idx & 15, mm = idx >> 4;
            int gm = m0 + mm, gk = kc + kk;
            float v = 0.0f;
            if (gm < M && gk < K) {
                size_t o = (size_t)gm * K + gk;
                v = A_DYN ? ldf(A, o, bf) : ((const float*)A)[o];
            }
            As[kk][mm] = v;
        }
#pragma unroll
        for (int j = 0; j < 4; j++) {
            int idx = tid + j * 256;
            int nn = idx & 63, kk = idx >> 6;
            int gk = kc + kk, gn = n0 + nn;
            Bs[kk][nn] = (gk < K && gn < Nn) ? ldf(B, (size_t)gk * Nn + gn, bf) : 0.0f;
        }
        __syncthreads();
#pragma unroll
        for (int kk = 0; kk < 16; kk++) {
            float4 a4 = *(const float4*)&As[kk][ty * 4];
            float4 b4 = *(const float4*)&Bs[kk][tx * 4];
            float av[4] = {a4.x, a4.y, a4.z, a4.w};
            float bv[4] = {b4.x, b4.y, b4.z, b4.w};
#pragma unroll
            for (int i = 0; i < 4; i++)
#pragma unroll
                for (int j = 0; j < 4; j++) acc[i][j] += av[i] * bv[j];
        }
        __syncthreads();
    }

#pragma unroll
    for (int i = 0; i < 4; i++) {
        int m = m0 + ty * 4 + i;
        if (m >= M) continue;
        float sc = SCALE ? dinv[m] : 1.0f;
#pragma unroll
        for (int j = 0; j < 4; j++) {
            int n = n0 + tx * 4 + j;
            if (n >= Nn) continue;
            float v = acc[i][j];
            if (bias) v += ldf(bias, n, bf);
            if (SCALE) v *= sc;
            if (RELU) v = fmaxf(v, 0.0f);
            if (OUTBF) ((__hip_bfloat16*)C)[(size_t)m * Nn + n] = __float2bfloat16(v);
            else       ((float*)C)[(size_t)m * Nn + n] = v;
        }
    }
}

// ---------- B-operand prep: W[K,Nn] fp32 -> Bt[NnPad][2*Kp] bf16 ([hi | lo], transposed, zero-padded) ----------
__global__ __launch_bounds__(256) void k_prep_b(const float* __restrict__ W,
                                                unsigned short* __restrict__ Bt,
                                                int K, int Nn, int Kp, int NnPad,
                                                const int* __restrict__ flags) {
    if (flags[0]) return;
    int idx = blockIdx.x * 256 + threadIdx.x;
    if (idx >= NnPad * Kp) return;
    int n = idx / Kp, k = idx - n * Kp;
    float v = (n < Nn && k < K) ? W[(size_t)k * Nn + n] : 0.0f;
    unsigned short h, l;
    split2(v, h, l);
    Bt[(size_t)n * (2 * Kp) + k] = h;
    Bt[(size_t)n * (2 * Kp) + Kp + k] = l;
}

// ---------- split-bf16 MFMA GEMM (fp32-accurate): C = A(fp32) @ W via Ahi*Bhi + Ahi*Blo + Alo*Bhi ----------
// Tile 128x128, BK=32, 4 waves (2x2), per-wave 64x64 = 4x4 frags of 16x16x32.
// T14 reg-prefetch + LDS DOUBLE-BUFFER (1 barrier/K-step) + bijective XCD swizzle
// so the n-tiles sharing an A m-panel land on the same XCD's L2.
typedef __bf16 bf16x8 __attribute__((ext_vector_type(8)));
typedef float f32x4 __attribute__((ext_vector_type(4)));

template <bool RELU, bool SCALE, bool HAS_BIAS, bool OUTBF>
__global__ __launch_bounds__(256) void k_gemm_mfma_split(const float* __restrict__ A,
                                                         const unsigned short* __restrict__ Bt,
                                                         const float* __restrict__ bias,
                                                         const float* __restrict__ dinv,
                                                         void* __restrict__ C,
                                                         int M, int K, int Kp, int Nn,
                                                         const int* __restrict__ flags) {
    if (flags[0]) return;  // bf16-input mode handled by k_gemm
    __shared__ unsigned short As_hi[2][4096], As_lo[2][4096];  // 2 x (128 rows x 32 k), swizzled
    __shared__ unsigned short Bs_hi[2][4096], Bs_lo[2][4096];
    const int tid = threadIdx.x;
    // bijective XCD-aware swizzle (work id w; consecutive same-XCD w share m-panel)
    const int nbx = gridDim.x;
    const int Wt = nbx * gridDim.y;
    const int li = blockIdx.x + nbx * blockIdx.y;
    const int q8 = Wt >> 3, r8 = Wt & 7;
    const int xk = li & 7, xj = li >> 3;
    const int wid = (xk < r8 ? xk * (q8 + 1) : r8 * (q8 + 1) + (xk - r8) * q8) + xj;
    const int n0 = (wid % nbx) * 128;
    const int m0 = (wid / nbx) * 128;
    const int w = tid >> 6, l = tid & 63;
    const int wm = (w >> 1) * 64, wn = (w & 1) * 64;
    const int lr = l & 15, ls = l >> 4;
    f32x4 acc[4][4] = {};

    // per-thread staged regs
    float4 stA0, stA1, stA2, stA3;
    uint4  stB0, stB1, stB2, stB3;

#define LOAD_TILE(kc_)                                                              \
    {                                                                               \
        int kc = (kc_);                                                             \
        {                                                                           \
            int c, r, q, gm, gk;                                                    \
            c = tid;           r = c >> 3; q = c & 7; gm = m0 + r; gk = kc + q * 4; \
            stA0 = (gm < M && gk < K) ? *(const float4*)(A + (size_t)gm * K + gk) : make_float4(0.f,0.f,0.f,0.f); \
            c = tid + 256;     r = c >> 3; q = c & 7; gm = m0 + r; gk = kc + q * 4; \
            stA1 = (gm < M && gk < K) ? *(const float4*)(A + (size_t)gm * K + gk) : make_float4(0.f,0.f,0.f,0.f); \
            c = tid + 512;     r = c >> 3; q = c & 7; gm = m0 + r; gk = kc + q * 4; \
            stA2 = (gm < M && gk < K) ? *(const float4*)(A + (size_t)gm * K + gk) : make_float4(0.f,0.f,0.f,0.f); \
            c = tid + 768;     r = c >> 3; q = c & 7; gm = m0 + r; gk = kc + q * 4; \
            stA3 = (gm < M && gk < K) ? *(const float4*)(A + (size_t)gm * K + gk) : make_float4(0.f,0.f,0.f,0.f); \
        }                                                                           \
        {                                                                           \
            int c, r, q, gn;                                                        \
            c = tid;       r = c >> 2; q = c & 3; gn = n0 + r;                      \
            stB0 = *(const uint4*)(Bt + (size_t)gn * (2 * Kp) + kc + q * 8);        \
            c = tid + 256; r = c >> 2; q = c & 3; gn = n0 + r;                      \
            stB1 = *(const uint4*)(Bt + (size_t)gn * (2 * Kp) + kc + q * 8);        \
            c = tid;       r = c >> 2; q = c & 3; gn = n0 + r;                      \
            stB2 = *(const uint4*)(Bt + (size_t)gn * (2 * Kp) + Kp + kc + q * 8);   \
            c = tid + 256; r = c >> 2; q = c & 3; gn = n0 + r;                      \
            stB3 = *(const uint4*)(Bt + (size_t)gn * (2 * Kp) + Kp + kc + q * 8);   \
        }                                                                           \
    }

#define WRITE_TILE(BUF)                                                             \
    {                                                                               \
        float4 va[4] = {stA0, stA1, stA2, stA3};                                    \
        _Pragma("unroll")                                                           \
        for (int j = 0; j < 4; j++) {                                               \
            int c = tid + j * 256;                                                  \
            int r = c >> 3, q = c & 7;                                              \
            unsigned short h0,h1,h2,h3,l0,l1,l2,l3;                                 \
            split2(va[j].x, h0, l0); split2(va[j].y, h1, l1);                       \
            split2(va[j].z, h2, l2); split2(va[j].w, h3, l3);                       \
            int waddr = r * 64 + (((q >> 1) ^ ((r >> 1) & 3)) << 4) + ((q & 1) << 3); \
            *(ushort4*)((char*)As_hi[BUF] + waddr) = make_ushort4(h0, h1, h2, h3);  \
            *(ushort4*)((char*)As_lo[BUF] + waddr) = make_ushort4(l0, l1, l2, l3);  \
        }                                                                           \
        {                                                                           \
            int c, r, q, waddr;                                                     \
            c = tid;       r = c >> 2; q = c & 3; waddr = r * 64 + ((q ^ ((r >> 1) & 3)) << 4); \
            *(uint4*)((char*)Bs_hi[BUF] + waddr) = stB0;                            \
            c = tid + 256; r = c >> 2; q = c & 3; waddr = r * 64 + ((q ^ ((r >> 1) & 3)) << 4); \
            *(uint4*)((char*)Bs_hi[BUF] + waddr) = stB1;                            \
            c = tid;       r = c >> 2; q = c & 3; waddr = r * 64 + ((q ^ ((r >> 1) & 3)) << 4); \
            *(uint4*)((char*)Bs_lo[BUF] + waddr) = stB2;                            \
            c = tid + 256; r = c >> 2; q = c & 3; waddr = r * 64 + ((q ^ ((r >> 1) & 3)) << 4); \
            *(uint4*)((char*)Bs_lo[BUF] + waddr) = stB3;                            \
        }                                                                           \
    }

    const int nsteps = (K + 31) / 32;
    LOAD_TILE(0);
    WRITE_TILE(0);
    __syncthreads();
    int cur = 0;
    for (int kt = 0; kt < nsteps; kt++) {
        if (kt + 1 < nsteps) LOAD_TILE((kt + 1) * 32);  // global prefetch, hides under MFMAs
        bf16x8 ah[4], al[4], bh[4], bl[4];
#pragma unroll
        for (int fm = 0; fm < 4; fm++) {
            int rr = wm + fm * 16 + lr;
            int addr = rr * 64 + ((ls ^ ((rr >> 1) & 3)) << 4);
            ah[fm] = *(const bf16x8*)((const char*)As_hi[cur] + addr);
            al[fm] = *(const bf16x8*)((const char*)As_lo[cur] + addr);
        }
#pragma unroll
        for (int fn = 0; fn < 4; fn++) {
            int cc2 = wn + fn * 16 + lr;
            int addr = cc2 * 64 + ((ls ^ ((cc2 >> 1) & 3)) << 4);
            bh[fn] = *(const bf16x8*)((const char*)Bs_hi[cur] + addr);
            bl[fn] = *(const bf16x8*)((const char*)Bs_lo[cur] + addr);
        }
#pragma unroll
        for (int fm = 0; fm < 4; fm++)
#pragma unroll
            for (int fn = 0; fn < 4; fn++) {
                acc[fm][fn] = __builtin_amdgcn_mfma_f32_16x16x32_bf16(ah[fm], bh[fn], acc[fm][fn], 0, 0, 0);
                acc[fm][fn] = __builtin_amdgcn_mfma_f32_16x16x32_bf16(ah[fm], bl[fn], acc[fm][fn], 0, 0, 0);
                acc[fm][fn] = __builtin_amdgcn_mfma_f32_16x16x32_bf16(al[fm], bh[fn], acc[fm][fn], 0, 0, 0);
            }
        if (kt + 1 < nsteps) {
            WRITE_TILE(cur ^ 1);  // write other buffer; readers of it synced below
            __syncthreads();
            cur ^= 1;
        }
    }
#undef LOAD_TILE
#undef WRITE_TILE

    // epilogue: C/D layout col=lane&15, row=(lane>>4)*4+reg [m89-verified]
#pragma unroll
    for (int fm = 0; fm < 4; fm++) {
#pragma unroll
        for (int j = 0; j < 4; j++) {
            int m = m0 + wm + fm * 16 + ls * 4 + j;
            if (m >= M) continue;
            float sc = SCALE ? dinv[m] : 1.0f;
#pragma unroll
            for (int fn = 0; fn < 4; fn++) {
                int n = n0 + wn + fn * 16 + lr;
                if (n >= Nn) continue;
                float v = acc[fm][fn][j];
                if (HAS_BIAS) v += bias[n];
                if (SCALE) v *= sc;
                if (RELU) v = fmaxf(v, 0.0f);
                if (OUTBF) ((__hip_bfloat16*)C)[(size_t)m * Nn + n] = __float2bfloat16(v);
                else       ((float*)C)[(size_t)m * Nn + n] = v;
            }
        }
    }
}

// ---------- small GEMM3: h2p[N,16] = (H2[N,100] @ W2[100,16]) * dinv ----------
__global__ __launch_bounds__(256) void k_gemm3(const float* __restrict__ H2,
                                               const void* __restrict__ W2,
                                               const float* __restrict__ dinv,
                                               float* __restrict__ h2p,
                                               const int* __restrict__ flags) {
    __shared__ float Ws[H2D * CC];
    const int bf = flags[0];
    int tid = threadIdx.x;
    for (int i = tid; i < H2D * CC; i += 256) Ws[i] = ldf(W2, i, bf);
    __syncthreads();
    int n = tid & 15, r = tid >> 4;
    int row = blockIdx.x * 16 + r;
    if (row >= NN) return;
    const float* h = H2 + (size_t)row * H2D;
    float acc = 0.0f;
#pragma unroll 4
    for (int k = 0; k < H2D; k++) acc += h[k] * Ws[k * CC + n];
    h2p[(size_t)row * CC + n] = acc * dinv[row];
}

// ---------- aggregation 1: h1p is bf16-packed (50 uints/row); wave-per-node, 2 feats/lane ----------
__global__ __launch_bounds__(256) void k_agg1(const unsigned short* __restrict__ h1p_bf,
                                              const int* __restrict__ row_ptr,
                                              const int* __restrict__ csr_src,
                                              const float* __restrict__ dinv,
                                              const void* __restrict__ b1,
                                              float* __restrict__ H2,
                                              const int* __restrict__ flags) {
    int lane = threadIdx.x & 63;
    int node = blockIdx.x * 4 + (threadIdx.x >> 6);
    if (node >= NN || lane >= 50) return;
    const unsigned int* rows = (const unsigned int*)h1p_bf;  // 50 uints per node
    float2 s = bf2f2(rows[(size_t)node * 50 + lane]);  // self loop
    float a0x = s.x, a0y = s.y;
    float a1x = 0.f, a1y = 0.f, a2x = 0.f, a2y = 0.f, a3x = 0.f, a3y = 0.f;
    int lo = row_ptr[node], hi = row_ptr[node + 1];
    int e = lo;
    for (; e + 3 < hi; e += 4) {
        int s0 = csr_src[e], s1 = csr_src[e + 1], s2 = csr_src[e + 2], s3 = csr_src[e + 3];
        float2 v0 = bf2f2(rows[(size_t)s0 * 50 + lane]);
        float2 v1 = bf2f2(rows[(size_t)s1 * 50 + lane]);
        float2 v2 = bf2f2(rows[(size_t)s2 * 50 + lane]);
        float2 v3 = bf2f2(rows[(size_t)s3 * 50 + lane]);
        a0x += v0.x; a0y += v0.y;
        a1x += v1.x; a1y += v1.y;
        a2x += v2.x; a2y += v2.y;
        a3x += v3.x; a3y += v3.y;
    }
    for (; e < hi; e++) {
        float2 v = bf2f2(rows[(size_t)csr_src[e] * 50 + lane]);
        a0x += v.x; a0y += v.y;
    }
    float sx = (a0x + a1x) + (a2x + a3x);
    float sy = (a0y + a1y) + (a2y + a3y);
    float di = dinv[node];
    int f = lane * 2;
    int bf = flags[0];
    float vx = fmaxf(sx * di + ldf(b1, f, bf), 0.0f);
    float vy = fmaxf(sy * di + ldf(b1, f + 1, bf), 0.0f);
    *(float2*)&H2[(size_t)node * H2D + f] = make_float2(vx, vy);
}

// ---------- aggregation 2 + bias + log_softmax (4-deep edge unroll) ----------
__global__ __launch_bounds__(256) void k_agg2(const float* __restrict__ h2p,
                                              const int* __restrict__ row_ptr,
                                              const int* __restrict__ csr_src,
                                              const float* __restrict__ dinv,
                                              const void* __restrict__ b2,
                                              void* __restrict__ out,
                                              const int* __restrict__ flags) {
    int tid = threadIdx.x;
    int n = tid & 15;
    int g = tid >> 4;  // 16 nodes per block
    int node = blockIdx.x * 16 + g;
    if (node >= NN) return;
    const int bf = flags[0];
    float a0 = h2p[(size_t)node * CC + n];  // self loop
    float a1 = 0.f, a2 = 0.f, a3 = 0.f;
    int lo = row_ptr[node], hi = row_ptr[node + 1];
    int e = lo;
    for (; e + 3 < hi; e += 4) {
        int s0 = csr_src[e], s1 = csr_src[e + 1], s2 = csr_src[e + 2], s3 = csr_src[e + 3];
        a0 += h2p[(size_t)s0 * CC + n];
        a1 += h2p[(size_t)s1 * CC + n];
        a2 += h2p[(size_t)s2 * CC + n];
        a3 += h2p[(size_t)s3 * CC + n];
    }
    for (; e < hi; e++) a0 += h2p[(size_t)csr_src[e] * CC + n];
    float acc = (a0 + a1) + (a2 + a3);
    float logit = acc * dinv[node] + ldf(b2, n, bf);
    float m = logit;
#pragma unroll
    for (int off = 1; off < 16; off <<= 1) m = fmaxf(m, __shfl_xor(m, off, 16));
    float ex = __expf(logit - m);
    float ssum = ex;
#pragma unroll
    for (int off = 1; off < 16; off <<= 1) ssum += __shfl_xor(ssum, off, 16);
    float r = logit - m - __logf(ssum);
    size_t oidx = (size_t)node * CC + n;
    if (bf) ((__hip_bfloat16*)out)[oidx] = __float2bfloat16(r);
    else    ((float*)out)[oidx] = r;
}

extern "C" void kernel_launch(void* const* d_in, const int* in_sizes, int n_in,
                              void* d_out, int out_size, void* d_ws, size_t ws_size,
                              hipStream_t stream) {
    const void* x     = d_in[0];
    const void* lin_W = d_in[1];
    const void* lin_b = d_in[2];
    const void* W1    = d_in[3];
    const void* b1    = d_in[4];
    const void* W2    = d_in[5];
    const void* b2    = d_in[6];
    const int*  ei    = (const int*)d_in[7];

    char* ws = (char*)d_ws;
    size_t off = 0;
    auto alloc = [&](size_t bytes) {
        off = (off + 255) & ~(size_t)255;
        void* p = ws + off;
        off += bytes;
        return p;
    };
    int*   flags   = (int*)alloc(2 * 4);
    int*   cnt     = (int*)alloc((size_t)NN * 4);
    int*   row_ptr = (int*)alloc((size_t)(NN + 1) * 4);
    int*   csr_src = (int*)alloc((size_t)EE * 4);
    float* dinv    = (float*)alloc((size_t)NN * 4);
    float* H1      = (float*)alloc((size_t)NN * H1D * 4);  // 60 MB
    float* H1p     = (float*)alloc((size_t)NN * H2D * 4);  // 20 MB slot (bf16 uses 10 MB)
    float* H2      = (float*)alloc((size_t)NN * H2D * 4);  // 20 MB
    float* h2p     = (float*)alloc((size_t)NN * CC * 4);   // 3.2 MB
    // pre-split transposed weights for MFMA path
    unsigned short* Bt1 = (unsigned short*)alloc((size_t)384 * 1024 * 2);  // [384][2*512]
    unsigned short* Bt2 = (unsigned short*)alloc((size_t)128 * 640 * 2);   // [128][2*320]

    const int gN = (NN + 255) / 256;
    const int gE = (EE + 255) / 256;

    k_sniff<<<1, 256, 0, stream>>>((const unsigned short*)x, (const unsigned int*)ei, flags);

    // CSR + degrees
    k_zero_cnt<<<gN, 256, 0, stream>>>(cnt);
    k_hist<<<gE, 256, 0, stream>>>(ei, cnt, flags);
    k_dinv<<<gN, 256, 0, stream>>>(cnt, dinv);
    k_scan<<<1, 1024, 0, stream>>>(cnt, row_ptr);
    k_scatter<<<gE, 256, 0, stream>>>(ei, row_ptr, cnt, csr_src, flags);

    // weight prep for split-MFMA path (no-op in bf16 mode)
    k_prep_b<<<(384 * 512 + 255) / 256, 256, 0, stream>>>(
        (const float*)lin_W, Bt1, FIN, H1D, 512, 384, flags);
    k_prep_b<<<(128 * 320 + 255) / 256, 256, 0, stream>>>(
        (const float*)W1, Bt2, H1D, H2D, 320, 128, flags);

    // H1 = relu(x @ lin_W + lin_b)  [fp32 mode: split-MFMA; bf16 mode: fallback]
    k_gemm_mfma_split<true, false, true, false><<<dim3(3, (NN + 127) / 128), 256, 0, stream>>>(
        (const float*)x, Bt1, (const float*)lin_b, nullptr, H1, NN, FIN, 512, H1D, flags);
    {
        dim3 grid((NN + 63) / 64, (H1D + 63) / 64);
        k_gemm<true, true, false, false><<<grid, 256, 0, stream>>>(
            x, lin_W, lin_b, nullptr, H1, NN, FIN, H1D, flags);
    }

    // H1p = (H1 @ W1) * dinv[row]  -> stored bf16 (agg1 reads packed pairs)
    k_gemm_mfma_split<false, true, false, true><<<dim3(1, (NN + 127) / 128), 256, 0, stream>>>(
        H1, Bt2, nullptr, dinv, H1p, NN, H1D, 320, H2D, flags);
    {
        dim3 grid((NN + 63) / 64, (H2D + 63) / 64);
        k_gemm<false, false, true, true><<<grid, 256, 0, stream>>>(
            H1, W1, nullptr, dinv, H1p, NN, H1D, H2D, flags);
    }

    // H2 = relu(dinv * (gather-sum H1p) + b1)
    k_agg1<<<(NN + 3) / 4, 256, 0, stream>>>((const unsigned short*)H1p, row_ptr, csr_src,
                                             dinv, b1, H2, flags);
    // h2p = (H2 @ W2) * dinv[row]
    k_gemm3<<<(NN + 15) / 16, 256, 0, stream>>>(H2, W2, dinv, h2p, flags);
    // out = log_softmax(dinv * (gather-sum h2p) + b2)
    k_agg2<<<(NN + 15) / 16, 256, 0, stream>>>(h2p, row_ptr, csr_src, dinv, b2, d_out, flags);
}

// Round 5
// 543.514 us; speedup vs baseline: 1.1609x; 1.1609x over previous
//
#include <hip/hip_runtime.h>
#include <hip/hip_bf16.h>

#define NN 50000
#define EE 800000
#define FIN 500
#define H1D 300
#define H2D 100
#define CC 16

// ---------- dtype-flexible load helpers ----------
__device__ __forceinline__ float ldf(const void* p, size_t i, int isbf16) {
    return isbf16 ? __bfloat162float(((const __hip_bfloat16*)p)[i])
                  : ((const float*)p)[i];
}
__device__ __forceinline__ int ld_src(const int* ei, int e, int is64) {
    return is64 ? ei[2 * (size_t)e] : ei[e];
}
__device__ __forceinline__ int ld_dst(const int* ei, int e, int is64) {
    return is64 ? ei[2 * ((size_t)EE + e)] : ei[(size_t)EE + e];
}

// split fp32 -> hi/lo bf16 bit patterns (hi+lo captures ~17 mantissa bits)
__device__ __forceinline__ void split2(float f, unsigned short& h, unsigned short& l) {
    __bf16 hb = (__bf16)f;
    float fh = (float)hb;
    __bf16 lb = (__bf16)(f - fh);
    h = __builtin_bit_cast(unsigned short, hb);
    l = __builtin_bit_cast(unsigned short, lb);
}

// unpack 2 packed bf16 (low = even feature, high = odd feature) to float2
__device__ __forceinline__ float2 bf2f2(unsigned int v) {
    float lo = __builtin_bit_cast(float, v << 16);
    float hi = __builtin_bit_cast(float, v & 0xffff0000u);
    return make_float2(lo, hi);
}

// ---------- dtype sniffing ----------
// flags[0]=1 if floats are stored as bf16, 0 if fp32.
// flags[1]=1 if edge_index is int64, 0 if int32.
__global__ void k_sniff(const unsigned short* __restrict__ xw,
                        const unsigned int* __restrict__ ew,
                        int* __restrict__ flags) {
    __shared__ int c_sane, c_zero;
    if (threadIdx.x == 0) { c_sane = 0; c_zero = 0; }
    __syncthreads();
    int t = threadIdx.x;  // 256 threads, 4 samples each
    int sane = 0, zer = 0;
    for (int j = 0; j < 4; j++) {
        unsigned short w = xw[t * 4 + j];
        int ex = (w >> 7) & 0xFF;
        if (w == 0 || (ex >= 100 && ex <= 150)) sane++;     // plausible bf16 of N(0,1)
        if (ew[2 * (t * 4 + j) + 1] == 0u) zer++;           // int64 high words
    }
    atomicAdd(&c_sane, sane);
    atomicAdd(&c_zero, zer);
    __syncthreads();
    if (threadIdx.x == 0) {
        flags[0] = (c_sane > 820) ? 1 : 0;  // >80% of 1024
        flags[1] = (c_zero > 512) ? 1 : 0;  // >50% of 1024
    }
}

// ---------- degree / CSR build ----------
__global__ void k_zero_cnt(int* __restrict__ cnt) {
    int i = blockIdx.x * blockDim.x + threadIdx.x;
    if (i < NN) cnt[i] = 0;
}

__global__ void k_hist(const int* __restrict__ ei, int* __restrict__ cnt,
                       const int* __restrict__ flags) {
    int e = blockIdx.x * blockDim.x + threadIdx.x;
    int is64 = flags[1];
    if (e < EE) {
        int d = ld_dst(ei, e, is64);
        if ((unsigned)d < NN) atomicAdd(&cnt[d], 1);
    }
}

__global__ void k_dinv(const int* __restrict__ cnt, float* __restrict__ dinv) {
    int i = blockIdx.x * blockDim.x + threadIdx.x;
    if (i < NN) dinv[i] = rsqrtf((float)cnt[i] + 1.0f);  // +1 self loop, deg>=1
}

__global__ __launch_bounds__(1024) void k_scan(int* __restrict__ cnt, int* __restrict__ row_ptr) {
    const int T = 1024;
    const int chunk = (NN + T - 1) / T;  // 49
    int t = threadIdx.x;
    int lo = t * chunk;
    int hi = lo + chunk; if (hi > NN) hi = NN; if (lo > NN) lo = NN;
    int s = 0;
    for (int i = lo; i < hi; i++) s += cnt[i];
    __shared__ int sums[T];
    sums[t] = s;
    __syncthreads();
    for (int off = 1; off < T; off <<= 1) {
        int v = (t >= off) ? sums[t - off] : 0;
        __syncthreads();
        sums[t] += v;
        __syncthreads();
    }
    int run = sums[t] - s;  // exclusive prefix
    for (int i = lo; i < hi; i++) {
        int c = cnt[i];
        row_ptr[i] = run;
        run += c;
        cnt[i] = 0;  // reuse cnt as fill counter for scatter
    }
    if (t == T - 1) row_ptr[NN] = run;
}

__global__ void k_scatter(const int* __restrict__ ei, const int* __restrict__ row_ptr,
                          int* __restrict__ fill, int* __restrict__ csr_src,
                          const int* __restrict__ flags) {
    int e = blockIdx.x * blockDim.x + threadIdx.x;
    int is64 = flags[1];
    if (e < EE) {
        int s = ld_src(ei, e, is64);
        int d = ld_dst(ei, e, is64);
        if ((unsigned)d < NN) {
            int pos = row_ptr[d] + atomicAdd(&fill[d], 1);
            csr_src[pos] = s;
        }
    }
}

// ---------- bf16-input fallback tiled GEMM (runs only when flags[0]==1) ----------
template <bool A_DYN, bool RELU, bool SCALE, bool OUTBF>
__global__ __launch_bounds__(256) void k_gemm(const void* __restrict__ A,
                                              const void* __restrict__ B,
                                              const void* __restrict__ bias,
                                              const float* __restrict__ dinv,
                                              void* __restrict__ C,
                                              int M, int K, int Nn,
                                              const int* __restrict__ flags) {
    if (!flags[0]) return;  // fp32 mode handled by split-MFMA kernel
    __shared__ float As[16][68];  // [k][m], padded
    __shared__ float Bs[16][68];  // [k][n]
    const int bf = flags[0];
    const int tid = threadIdx.x;
    const int m0 = blockIdx.x * 64, n0 = blockIdx.y * 64;
    const int tx = tid & 15;   // n group (4 cols)
    const int ty = tid >> 4;   // m group (4 rows)
    float acc[4][4] = {};

    for (int kc = 0; kc < K; kc += 16) {
#pragma unroll
        for (int j = 0; j < 4; j++) {
            int idx = tid + j * 256;
            int kk = idx & 15, mm = idx >> 4;
            int gm = m0 + mm, gk = kc + kk;
            float v = 0.0f;
            if (gm < M && gk < K) {
                size_t o = (size_t)gm * K + gk;
                v = A_DYN ? ldf(A, o, bf) : ((const float*)A)[o];
            }
            As[kk][mm] = v;
        }
#pragma unroll
        for (int j = 0; j < 4; j++) {
            int idx = tid + j * 256;
            int nn = idx & 63, kk = idx >> 6;
            int gk = kc + kk, gn = n0 + nn;
            Bs[kk][nn] = (gk < K && gn < Nn) ? ldf(B, (size_t)gk * Nn + gn, bf) : 0.0f;
        }
        __syncthreads();
#pragma unroll
        for (int kk = 0; kk < 16; kk++) {
            float4 a4 = *(const float4*)&As[kk][ty * 4];
            float4 b4 = *(const float4*)&Bs[kk][tx * 4];
            float av[4] = {a4.x, a4.y, a4.z, a4.w};
            float bv[4] = {b4.x, b4.y, b4.z, b4.w};
#pragma unroll
            for (int i = 0; i < 4; i++)
#pragma unroll
                for (int j = 0; j < 4; j++) acc[i][j] += av[i] * bv[j];
        }
        __syncthreads();
    }

#pragma unroll
    for (int i = 0; i < 4; i++) {
        int m = m0 + ty * 4 + i;
        if (m >= M) continue;
        float sc = SCALE ? dinv[m] : 1.0f;
#pragma unroll
        for (int j = 0; j < 4; j++) {
            int n = n0 + tx * 4 + j;
            if (n >= Nn) continue;
            float v = acc[i][j];
            if (bias) v += ldf(bias, n, bf);
            if (SCALE) v *= sc;
            if (RELU) v = fmaxf(v, 0.0f);
            if (OUTBF) ((__hip_bfloat16*)C)[(size_t)m * Nn + n] = __float2bfloat16(v);
            else       ((float*)C)[(size_t)m * Nn + n] = v;
        }
    }
}

// ---------- B-operand prep: W[K,Nn] fp32 -> Bt[NnPad][2*Kp] bf16 ([hi | lo], transposed, zero-padded) ----------
__global__ __launch_bounds__(256) void k_prep_b(const float* __restrict__ W,
                                                unsigned short* __restrict__ Bt,
                                                int K, int Nn, int Kp, int NnPad,
                                                const int* __restrict__ flags) {
    if (flags[0]) return;
    int idx = blockIdx.x * 256 + threadIdx.x;
    if (idx >= NnPad * Kp) return;
    int n = idx / Kp, k = idx - n * Kp;
    float v = (n < Nn && k < K) ? W[(size_t)k * Nn + n] : 0.0f;
    unsigned short h, l;
    split2(v, h, l);
    Bt[(size_t)n * (2 * Kp) + k] = h;
    Bt[(size_t)n * (2 * Kp) + Kp + k] = l;
}

// ---------- split-bf16 MFMA GEMM (fp32-accurate): C = A(fp32) @ W via Ahi*Bhi + Ahi*Blo + Alo*Bhi ----------
// Tile 128x128, BK=32, 4 waves (2x2), per-wave 64x64 = 4x4 frags of 16x16x32.
// R3-proven single-buffer 32KB LDS (5 blocks/CU) + T14 reg-prefetch + XCD swizzle.
// // 64KB double-buffer regressed (R4): blocks/CU 5->2, latency-bound kernel lost TLP.
typedef __bf16 bf16x8 __attribute__((ext_vector_type(8)));
typedef float f32x4 __attribute__((ext_vector_type(4)));

template <bool RELU, bool SCALE, bool HAS_BIAS, bool OUTBF>
__global__ __launch_bounds__(256) void k_gemm_mfma_split(const float* __restrict__ A,
                                                         const unsigned short* __restrict__ Bt,
                                                         const float* __restrict__ bias,
                                                         const float* __restrict__ dinv,
                                                         void* __restrict__ C,
                                                         int M, int K, int Kp, int Nn,
                                                         const int* __restrict__ flags) {
    if (flags[0]) return;  // bf16-input mode handled by k_gemm
    __shared__ unsigned short As_hi[4096], As_lo[4096];  // 128 rows x 32 k, swizzled
    __shared__ unsigned short Bs_hi[4096], Bs_lo[4096];
    const int tid = threadIdx.x;
    // bijective XCD-aware swizzle: consecutive same-XCD work ids share the A m-panel
    const int nbx = gridDim.x;
    const int Wt = nbx * gridDim.y;
    const int li = blockIdx.x + nbx * blockIdx.y;
    const int q8 = Wt >> 3, r8 = Wt & 7;
    const int xk = li & 7, xj = li >> 3;
    const int wid = (xk < r8 ? xk * (q8 + 1) : r8 * (q8 + 1) + (xk - r8) * q8) + xj;
    const int n0 = (wid % nbx) * 128;
    const int m0 = (wid / nbx) * 128;
    const int w = tid >> 6, l = tid & 63;
    const int wm = (w >> 1) * 64, wn = (w & 1) * 64;
    const int lr = l & 15, ls = l >> 4;
    f32x4 acc[4][4] = {};

    // per-thread staged regs
    float4 stA0, stA1, stA2, stA3;
    uint4  stB0, stB1, stB2, stB3;

#define LOAD_TILE(kc_)                                                              \
    {                                                                               \
        int kc = (kc_);                                                             \
        {                                                                           \
            int c, r, q, gm, gk;                                                    \
            c = tid;           r = c >> 3; q = c & 7; gm = m0 + r; gk = kc + q * 4; \
            stA0 = (gm < M && gk < K) ? *(const float4*)(A + (size_t)gm * K + gk) : make_float4(0.f,0.f,0.f,0.f); \
            c = tid + 256;     r = c >> 3; q = c & 7; gm = m0 + r; gk = kc + q * 4; \
            stA1 = (gm < M && gk < K) ? *(const float4*)(A + (size_t)gm * K + gk) : make_float4(0.f,0.f,0.f,0.f); \
            c = tid + 512;     r = c >> 3; q = c & 7; gm = m0 + r; gk = kc + q * 4; \
            stA2 = (gm < M && gk < K) ? *(const float4*)(A + (size_t)gm * K + gk) : make_float4(0.f,0.f,0.f,0.f); \
            c = tid + 768;     r = c >> 3; q = c & 7; gm = m0 + r; gk = kc + q * 4; \
            stA3 = (gm < M && gk < K) ? *(const float4*)(A + (size_t)gm * K + gk) : make_float4(0.f,0.f,0.f,0.f); \
        }                                                                           \
        {                                                                           \
            int c, r, q, gn;                                                        \
            c = tid;       r = c >> 2; q = c & 3; gn = n0 + r;                      \
            stB0 = *(const uint4*)(Bt + (size_t)gn * (2 * Kp) + kc + q * 8);        \
            c = tid + 256; r = c >> 2; q = c & 3; gn = n0 + r;                      \
            stB1 = *(const uint4*)(Bt + (size_t)gn * (2 * Kp) + kc + q * 8);        \
            c = tid;       r = c >> 2; q = c & 3; gn = n0 + r;                      \
            stB2 = *(const uint4*)(Bt + (size_t)gn * (2 * Kp) + Kp + kc + q * 8);   \
            c = tid + 256; r = c >> 2; q = c & 3; gn = n0 + r;                      \
            stB3 = *(const uint4*)(Bt + (size_t)gn * (2 * Kp) + Kp + kc + q * 8);   \
        }                                                                           \
    }

#define WRITE_TILE()                                                                \
    {                                                                               \
        float4 va[4] = {stA0, stA1, stA2, stA3};                                    \
        _Pragma("unroll")                                                           \
        for (int j = 0; j < 4; j++) {                                               \
            int c = tid + j * 256;                                                  \
            int r = c >> 3, q = c & 7;                                              \
            unsigned short h0,h1,h2,h3,l0,l1,l2,l3;                                 \
            split2(va[j].x, h0, l0); split2(va[j].y, h1, l1);                       \
            split2(va[j].z, h2, l2); split2(va[j].w, h3, l3);                       \
            int waddr = r * 64 + (((q >> 1) ^ ((r >> 1) & 3)) << 4) + ((q & 1) << 3); \
            *(ushort4*)((char*)As_hi + waddr) = make_ushort4(h0, h1, h2, h3);       \
            *(ushort4*)((char*)As_lo + waddr) = make_ushort4(l0, l1, l2, l3);       \
        }                                                                           \
        {                                                                           \
            int c, r, q, waddr;                                                     \
            c = tid;       r = c >> 2; q = c & 3; waddr = r * 64 + ((q ^ ((r >> 1) & 3)) << 4); \
            *(uint4*)((char*)Bs_hi + waddr) = stB0;                                 \
            c = tid + 256; r = c >> 2; q = c & 3; waddr = r * 64 + ((q ^ ((r >> 1) & 3)) << 4); \
            *(uint4*)((char*)Bs_hi + waddr) = stB1;                                 \
            c = tid;       r = c >> 2; q = c & 3; waddr = r * 64 + ((q ^ ((r >> 1) & 3)) << 4); \
            *(uint4*)((char*)Bs_lo + waddr) = stB2;                                 \
            c = tid + 256; r = c >> 2; q = c & 3; waddr = r * 64 + ((q ^ ((r >> 1) & 3)) << 4); \
            *(uint4*)((char*)Bs_lo + waddr) = stB3;                                 \
        }                                                                           \
    }

    const int nsteps = (K + 31) / 32;
    LOAD_TILE(0);
    for (int kt = 0; kt < nsteps; kt++) {
        WRITE_TILE();
        __syncthreads();
        if (kt + 1 < nsteps) LOAD_TILE((kt + 1) * 32);  // prefetch; drains at next-iter sync
        bf16x8 ah[4], al[4], bh[4], bl[4];
#pragma unroll
        for (int fm = 0; fm < 4; fm++) {
            int rr = wm + fm * 16 + lr;
            int addr = rr * 64 + ((ls ^ ((rr >> 1) & 3)) << 4);
            ah[fm] = *(const bf16x8*)((const char*)As_hi + addr);
            al[fm] = *(const bf16x8*)((const char*)As_lo + addr);
        }
#pragma unroll
        for (int fn = 0; fn < 4; fn++) {
            int cc2 = wn + fn * 16 + lr;
            int addr = cc2 * 64 + ((ls ^ ((cc2 >> 1) & 3)) << 4);
            bh[fn] = *(const bf16x8*)((const char*)Bs_hi + addr);
            bl[fn] = *(const bf16x8*)((const char*)Bs_lo + addr);
        }
#pragma unroll
        for (int fm = 0; fm < 4; fm++)
#pragma unroll
            for (int fn = 0; fn < 4; fn++) {
                acc[fm][fn] = __builtin_amdgcn_mfma_f32_16x16x32_bf16(ah[fm], bh[fn], acc[fm][fn], 0, 0, 0);
                acc[fm][fn] = __builtin_amdgcn_mfma_f32_16x16x32_bf16(ah[fm], bl[fn], acc[fm][fn], 0, 0, 0);
                acc[fm][fn] = __builtin_amdgcn_mfma_f32_16x16x32_bf16(al[fm], bh[fn], acc[fm][fn], 0, 0, 0);
            }
        __syncthreads();
    }
#undef LOAD_TILE
#undef WRITE_TILE

    // epilogue: C/D layout col=lane&15, row=(lane>>4)*4+reg [m89-verified]
#pragma unroll
    for (int fm = 0; fm < 4; fm++) {
#pragma unroll
        for (int j = 0; j < 4; j++) {
            int m = m0 + wm + fm * 16 + ls * 4 + j;
            if (m >= M) continue;
            float sc = SCALE ? dinv[m] : 1.0f;
#pragma unroll
            for (int fn = 0; fn < 4; fn++) {
                int n = n0 + wn + fn * 16 + lr;
                if (n >= Nn) continue;
                float v = acc[fm][fn][j];
                if (HAS_BIAS) v += bias[n];
                if (SCALE) v *= sc;
                if (RELU) v = fmaxf(v, 0.0f);
                if (OUTBF) ((__hip_bfloat16*)C)[(size_t)m * Nn + n] = __float2bfloat16(v);
                else       ((float*)C)[(size_t)m * Nn + n] = v;
            }
        }
    }
}

// ---------- small GEMM3: h2p[N,16] = (H2[N,100] @ W2[100,16]) * dinv ----------
__global__ __launch_bounds__(256) void k_gemm3(const float* __restrict__ H2,
                                               const void* __restrict__ W2,
                                               const float* __restrict__ dinv,
                                               float* __restrict__ h2p,
                                               const int* __restrict__ flags) {
    __shared__ float Ws[H2D * CC];
    const int bf = flags[0];
    int tid = threadIdx.x;
    for (int i = tid; i < H2D * CC; i += 256) Ws[i] = ldf(W2, i, bf);
    __syncthreads();
    int n = tid & 15, r = tid >> 4;
    int row = blockIdx.x * 16 + r;
    if (row >= NN) return;
    const float* h = H2 + (size_t)row * H2D;
    float acc = 0.0f;
#pragma unroll 4
    for (int k = 0; k < H2D; k++) acc += h[k] * Ws[k * CC + n];
    h2p[(size_t)row * CC + n] = acc * dinv[row];
}

// ---------- aggregation 1: h1p is bf16-packed (50 uints/row); wave-per-node, 2 feats/lane ----------
__global__ __launch_bounds__(256) void k_agg1(const unsigned short* __restrict__ h1p_bf,
                                              const int* __restrict__ row_ptr,
                                              const int* __restrict__ csr_src,
                                              const float* __restrict__ dinv,
                                              const void* __restrict__ b1,
                                              float* __restrict__ H2,
                                              const int* __restrict__ flags) {
    int lane = threadIdx.x & 63;
    int node = blockIdx.x * 4 + (threadIdx.x >> 6);
    if (node >= NN || lane >= 50) return;
    const unsigned int* rows = (const unsigned int*)h1p_bf;  // 50 uints per node
    float2 s = bf2f2(rows[(size_t)node * 50 + lane]);  // self loop
    float a0x = s.x, a0y = s.y;
    float a1x = 0.f, a1y = 0.f, a2x = 0.f, a2y = 0.f, a3x = 0.f, a3y = 0.f;
    int lo = row_ptr[node], hi = row_ptr[node + 1];
    int e = lo;
    for (; e + 3 < hi; e += 4) {
        int s0 = csr_src[e], s1 = csr_src[e + 1], s2 = csr_src[e + 2], s3 = csr_src[e + 3];
        float2 v0 = bf2f2(rows[(size_t)s0 * 50 + lane]);
        float2 v1 = bf2f2(rows[(size_t)s1 * 50 + lane]);
        float2 v2 = bf2f2(rows[(size_t)s2 * 50 + lane]);
        float2 v3 = bf2f2(rows[(size_t)s3 * 50 + lane]);
        a0x += v0.x; a0y += v0.y;
        a1x += v1.x; a1y += v1.y;
        a2x += v2.x; a2y += v2.y;
        a3x += v3.x; a3y += v3.y;
    }
    for (; e < hi; e++) {
        float2 v = bf2f2(rows[(size_t)csr_src[e] * 50 + lane]);
        a0x += v.x; a0y += v.y;
    }
    float sx = (a0x + a1x) + (a2x + a3x);
    float sy = (a0y + a1y) + (a2y + a3y);
    float di = dinv[node];
    int f = lane * 2;
    int bf = flags[0];
    float vx = fmaxf(sx * di + ldf(b1, f, bf), 0.0f);
    float vy = fmaxf(sy * di + ldf(b1, f + 1, bf), 0.0f);
    *(float2*)&H2[(size_t)node * H2D + f] = make_float2(vx, vy);
}

// ---------- aggregation 2 + bias + log_softmax (4-deep edge unroll) ----------
__global__ __launch_bounds__(256) void k_agg2(const float* __restrict__ h2p,
                                              const int* __restrict__ row_ptr,
                                              const int* __restrict__ csr_src,
                                              const float* __restrict__ dinv,
                                              const void* __restrict__ b2,
                                              void* __restrict__ out,
                                              const int* __restrict__ flags) {
    int tid = threadIdx.x;
    int n = tid & 15;
    int g = tid >> 4;  // 16 nodes per block
    int node = blockIdx.x * 16 + g;
    if (node >= NN) return;
    const int bf = flags[0];
    float a0 = h2p[(size_t)node * CC + n];  // self loop
    float a1 = 0.f, a2 = 0.f, a3 = 0.f;
    int lo = row_ptr[node], hi = row_ptr[node + 1];
    int e = lo;
    for (; e + 3 < hi; e += 4) {
        int s0 = csr_src[e], s1 = csr_src[e + 1], s2 = csr_src[e + 2], s3 = csr_src[e + 3];
        a0 += h2p[(size_t)s0 * CC + n];
        a1 += h2p[(size_t)s1 * CC + n];
        a2 += h2p[(size_t)s2 * CC + n];
        a3 += h2p[(size_t)s3 * CC + n];
    }
    for (; e < hi; e++) a0 += h2p[(size_t)csr_src[e] * CC + n];
    float acc = (a0 + a1) + (a2 + a3);
    float logit = acc * dinv[node] + ldf(b2, n, bf);
    float m = logit;
#pragma unroll
    for (int off = 1; off < 16; off <<= 1) m = fmaxf(m, __shfl_xor(m, off, 16));
    float ex = __expf(logit - m);
    float ssum = ex;
#pragma unroll
    for (int off = 1; off < 16; off <<= 1) ssum += __shfl_xor(ssum, off, 16);
    float r = logit - m - __logf(ssum);
    size_t oidx = (size_t)node * CC + n;
    if (bf) ((__hip_bfloat16*)out)[oidx] = __float2bfloat16(r);
    else    ((float*)out)[oidx] = r;
}

extern "C" void kernel_launch(void* const* d_in, const int* in_sizes, int n_in,
                              void* d_out, int out_size, void* d_ws, size_t ws_size,
                              hipStream_t stream) {
    const void* x     = d_in[0];
    const void* lin_W = d_in[1];
    const void* lin_b = d_in[2];
    const void* W1    = d_in[3];
    const void* b1    = d_in[4];
    const void* W2    = d_in[5];
    const void* b2    = d_in[6];
    const int*  ei    = (const int*)d_in[7];

    char* ws = (char*)d_ws;
    size_t off = 0;
    auto alloc = [&](size_t bytes) {
        off = (off + 255) & ~(size_t)255;
        void* p = ws + off;
        off += bytes;
        return p;
    };
    int*   flags   = (int*)alloc(2 * 4);
    int*   cnt     = (int*)alloc((size_t)NN * 4);
    int*   row_ptr = (int*)alloc((size_t)(NN + 1) * 4);
    int*   csr_src = (int*)alloc((size_t)EE * 4);
    float* dinv    = (float*)alloc((size_t)NN * 4);
    float* H1      = (float*)alloc((size_t)NN * H1D * 4);  // 60 MB
    float* H1p     = (float*)alloc((size_t)NN * H2D * 4);  // 20 MB slot (bf16 uses 10 MB)
    float* H2      = (float*)alloc((size_t)NN * H2D * 4);  // 20 MB
    float* h2p     = (float*)alloc((size_t)NN * CC * 4);   // 3.2 MB
    // pre-split transposed weights for MFMA path
    unsigned short* Bt1 = (unsigned short*)alloc((size_t)384 * 1024 * 2);  // [384][2*512]
    unsigned short* Bt2 = (unsigned short*)alloc((size_t)128 * 640 * 2);   // [128][2*320]

    const int gN = (NN + 255) / 256;
    const int gE = (EE + 255) / 256;

    k_sniff<<<1, 256, 0, stream>>>((const unsigned short*)x, (const unsigned int*)ei, flags);

    // CSR + degrees
    k_zero_cnt<<<gN, 256, 0, stream>>>(cnt);
    k_hist<<<gE, 256, 0, stream>>>(ei, cnt, flags);
    k_dinv<<<gN, 256, 0, stream>>>(cnt, dinv);
    k_scan<<<1, 1024, 0, stream>>>(cnt, row_ptr);
    k_scatter<<<gE, 256, 0, stream>>>(ei, row_ptr, cnt, csr_src, flags);

    // weight prep for split-MFMA path (no-op in bf16 mode)
    k_prep_b<<<(384 * 512 + 255) / 256, 256, 0, stream>>>(
        (const float*)lin_W, Bt1, FIN, H1D, 512, 384, flags);
    k_prep_b<<<(128 * 320 + 255) / 256, 256, 0, stream>>>(
        (const float*)W1, Bt2, H1D, H2D, 320, 128, flags);

    // H1 = relu(x @ lin_W + lin_b)  [fp32 mode: split-MFMA; bf16 mode: fallback]
    k_gemm_mfma_split<true, false, true, false><<<dim3(3, (NN + 127) / 128), 256, 0, stream>>>(
        (const float*)x, Bt1, (const float*)lin_b, nullptr, H1, NN, FIN, 512, H1D, flags);
    {
        dim3 grid((NN + 63) / 64, (H1D + 63) / 64);
        k_gemm<true, true, false, false><<<grid, 256, 0, stream>>>(
            x, lin_W, lin_b, nullptr, H1, NN, FIN, H1D, flags);
    }

    // H1p = (H1 @ W1) * dinv[row]  -> stored bf16 (agg1 reads packed pairs)
    k_gemm_mfma_split<false, true, false, true><<<dim3(1, (NN + 127) / 128), 256, 0, stream>>>(
        H1, Bt2, nullptr, dinv, H1p, NN, H1D, 320, H2D, flags);
    {
        dim3 grid((NN + 63) / 64, (H2D + 63) / 64);
        k_gemm<false, false, true, true><<<grid, 256, 0, stream>>>(
            H1, W1, nullptr, dinv, H1p, NN, H1D, H2D, flags);
    }

    // H2 = relu(dinv * (gather-sum H1p) + b1)
    k_agg1<<<(NN + 3) / 4, 256, 0, stream>>>((const unsigned short*)H1p, row_ptr, csr_src,
                                             dinv, b1, H2, flags);
    // h2p = (H2 @ W2) * dinv[row]
    k_gemm3<<<(NN + 15) / 16, 256, 0, stream>>>(H2, W2, dinv, h2p, flags);
    // out = log_softmax(dinv * (gather-sum h2p) + b2)
    k_agg2<<<(NN + 15) / 16, 256, 0, stream>>>(h2p, row_ptr, csr_src, dinv, b2, d_out, flags);
}